// Round 16
// baseline (301.749 us; speedup 1.0000x reference)
//
#include <hip/hip_runtime.h>
#include <hip/hip_fp16.h>
#include <stdint.h>
#include <math.h>

#define NH    12
#define SEQ   2048
#define BATCH 2
#define DM    768
#define HD    64
#define SCALEF 0.125f      // 1/sqrt(64)

typedef unsigned short u16;
typedef unsigned int   u32;
typedef unsigned long long u64;
typedef __attribute__((ext_vector_type(8))) short bf16x8;
typedef __attribute__((ext_vector_type(8))) _Float16 h16x8;
typedef __attribute__((ext_vector_type(2))) unsigned short u16x2;
typedef __attribute__((ext_vector_type(4))) float f32x4;

__device__ __forceinline__ u16 f2bf(float f){
  u32 u = __float_as_uint(f);
  u32 r = u + 0x7fffu + ((u >> 16) & 1u);
  return (u16)(r >> 16);
}
__device__ __forceinline__ u16 f2h(float f){ return __half_as_ushort(__float2half(f)); }
__device__ __forceinline__ float h2f(u16 x){ return __half2float(__ushort_as_half(x)); }

// async global->LDS 16B (HW: wave-uniform LDS base + lane*16; global src per-lane)
__device__ __forceinline__ void gload16(const u16* g, u16* l){
  __builtin_amdgcn_global_load_lds(
      (const __attribute__((address_space(1))) unsigned int*)g,
      (__attribute__((address_space(3))) unsigned int*)l, 16, 0, 0);
}

// order-preserving u16 key -> fp16 value
__device__ __forceinline__ float kval(u32 k){
  const u16 hb = (k & 0x8000u) ? (u16)(k & 0x7fffu) : (u16)(~k & 0xffffu);
  return h2f(hb);
}
__device__ __forceinline__ int cnt_ge(u32 dw, u32 tm){
  return (int)((dw & 0xffffu) >= tm) + (int)((dw >> 16) >= tm);
}

// ---- DPP wave64 reductions (VALU pipe, no LDS) ----
__device__ __forceinline__ int dpp_scan_incl(int x){
  x += __builtin_amdgcn_update_dpp(0, x, 0x111, 0xf, 0xf, true);
  x += __builtin_amdgcn_update_dpp(0, x, 0x112, 0xf, 0xf, true);
  x += __builtin_amdgcn_update_dpp(0, x, 0x114, 0xf, 0xf, true);
  x += __builtin_amdgcn_update_dpp(0, x, 0x118, 0xf, 0xf, true);
  x += __builtin_amdgcn_update_dpp(0, x, 0x142, 0xa, 0xf, true);
  x += __builtin_amdgcn_update_dpp(0, x, 0x143, 0xc, 0xf, true);
  return x;
}
__device__ __forceinline__ float dpp_sumf(float x){
  #define ASTEP(ctrl, rm) x += __int_as_float(__builtin_amdgcn_update_dpp(0, __float_as_int(x), ctrl, rm, 0xf, true));
  ASTEP(0x111,0xf) ASTEP(0x112,0xf) ASTEP(0x114,0xf) ASTEP(0x118,0xf) ASTEP(0x142,0xa) ASTEP(0x143,0xc)
  #undef ASTEP
  return __uint_as_float((u32)__builtin_amdgcn_readlane(__float_as_int(x), 63));
}
__device__ __forceinline__ int dpp_maxi(int x){
  #define ISTEP(ctrl, rm) { int o = x; int y = __builtin_amdgcn_update_dpp(o, o, ctrl, rm, 0xf, false); \
    x = (x > y) ? x : y; }
  ISTEP(0x111,0xf) ISTEP(0x112,0xf) ISTEP(0x114,0xf) ISTEP(0x118,0xf) ISTEP(0x142,0xa) ISTEP(0x143,0xc)
  #undef ISTEP
  return __builtin_amdgcn_readlane(x, 63);
}

// swizzled fp16 prob matrix P[16][2048] (u16 units)
__device__ __forceinline__ int pb_off(int q, int k){
  return (q << 11) + ((((k >> 3) ^ (q & 7)) << 3) | (k & 7));
}
// swizzled psum [4 kcopies][16 q][64 d] (f32 units)
__device__ __forceinline__ int ps_off(int kc, int q, int d){
  return (kc << 10) + (q << 6) + ((((d >> 2) ^ q) & 15) << 2) + (d & 3);
}

// ---------------------------------------------------------------- cvt fp32->bf16
__global__ void cvt_kernel(const float* s0, const float* s1, const float* s2, const float* s3,
                           u16* d0, u16* d1, u16* d2, u16* d3, int n){
  const float* s; u16* d;
  switch (blockIdx.y){
    case 0: s = s0; d = d0; break;
    case 1: s = s1; d = d1; break;
    case 2: s = s2; d = d2; break;
    default: s = s3; d = d3; break;
  }
  int i = (blockIdx.x * 256 + threadIdx.x) * 4;
  if (i < n){
    float4 v = *(const float4*)(s + i);
    ushort4 o;
    o.x = f2bf(v.x); o.y = f2bf(v.y); o.z = f2bf(v.z); o.w = f2bf(v.w);
    *(ushort4*)(d + i) = o;
  }
}

// ---------------------------------------------------------------- GEMM  C = A @ W^T (+bias)
// Staging via global_load_lds width=16 (linear LDS [128][32], no padding).
// MODE 0: zz=0,1 -> bf16 head-split [(b*NH+h)*SEQ+s]*HD+d ; zz=2 -> fp16 V^T [(b*NH+h)*HD+d]*SEQ+s
// MODE 1: out fp32 plain [m][n]
template<int MODE>
__global__ __launch_bounds__(256) void gemm_bt(const u16* __restrict__ Aall, const u16* __restrict__ Wall,
      const float* __restrict__ bz0, const float* __restrict__ bz1, const float* __restrict__ bz2,
      u16* __restrict__ outb, float* __restrict__ outf){
  __shared__ u16 As[128 * 32];
  __shared__ u16 Bs[128 * 32];
  const int zz = blockIdx.z;
  const u16* A = Aall + (size_t)zz * 4096 * 768;
  const u16* W = Wall + (size_t)zz * 768 * 768;
  const float* bias = (zz == 0) ? bz0 : (zz == 1 ? bz1 : bz2);
  const int m0 = blockIdx.x * 128, n0 = blockIdx.y * 128;
  const int t = threadIdx.x, lane = t & 63, wv = t >> 6;
  const int wm = wv >> 1, wn = wv & 1;
  f32x4 acc[4][4] = {};
  const int srow = t >> 2;              // staged row 0..63 (call j adds 64)
  const int scol = (t & 3) * 8;         // bf16 col within 32
  const u16* ag = A + (size_t)(m0 + srow) * 768 + scol;
  const u16* bg = W + (size_t)(n0 + srow) * 768 + scol;
  u16* al = As + t * 8;                 // linear: u16 off t*8 == srow*32 + scol
  u16* bl = Bs + t * 8;
  for (int kt = 0; kt < 768; kt += 32){
    __syncthreads();                    // prior reads done before overwrite
    gload16(ag + kt,            al);
    gload16(ag + kt + 64 * 768, al + 2048);
    gload16(bg + kt,            bl);
    gload16(bg + kt + 64 * 768, bl + 2048);
    __syncthreads();                    // drains vmcnt -> LDS ready
    bf16x8 af[4], bq[4];
    #pragma unroll
    for (int i = 0; i < 4; ++i) af[i] = *(const bf16x8*)&As[(wm*64 + i*16 + (lane & 15)) * 32 + (lane >> 4) * 8];
    #pragma unroll
    for (int i = 0; i < 4; ++i) bq[i] = *(const bf16x8*)&Bs[(wn*64 + i*16 + (lane & 15)) * 32 + (lane >> 4) * 8];
    #pragma unroll
    for (int mi = 0; mi < 4; ++mi)
      #pragma unroll
      for (int ni = 0; ni < 4; ++ni)
        acc[mi][ni] = __builtin_amdgcn_mfma_f32_16x16x32_bf16(af[mi], bq[ni], acc[mi][ni], 0, 0, 0);
  }
  #pragma unroll
  for (int mi = 0; mi < 4; ++mi){
    #pragma unroll
    for (int ni = 0; ni < 4; ++ni){
      const int n = n0 + wn*64 + ni*16 + (lane & 15);
      const float bval = bias[n];
      const int mbase = m0 + wm*64 + mi*16 + (lane >> 4) * 4;
      if (MODE == 0 && zz == 2){
        const int bb = mbase >> 11, ss = mbase & 2047;
        const int hh = n >> 6, dd = n & 63;
        u64 pk = 0;
        #pragma unroll
        for (int r = 0; r < 4; ++r) pk |= (u64)f2h(acc[mi][ni][r] + bval) << (16 * r);
        *(u64*)(outb + (size_t)2 * 3145728 + (((size_t)(bb * NH + hh) * HD + dd) * SEQ + ss)) = pk;
      } else if (MODE == 0){
        #pragma unroll
        for (int r = 0; r < 4; ++r){
          const int m = mbase + r;
          const int bb = m >> 11, ss = m & 2047, hh = n >> 6, dd = n & 63;
          outb[(size_t)zz * 3145728 + (((size_t)bb * NH + hh) * SEQ + ss) * HD + dd] = f2bf(acc[mi][ni][r] + bval);
        }
      } else {
        #pragma unroll
        for (int r = 0; r < 4; ++r){
          const int m = mbase + r;
          outf[(size_t)m * DM + n] = acc[mi][ni][r] + bval;
        }
      }
    }
  }
}

// ---------------------------------------------------------------- fused attention v14
// v13 structure; bracket probe merged with compaction (scan_incl gives prefix+total,
// success writes candidates in-loop); window softmax reuses m1 (row max) -> no wm chain.
__global__ __launch_bounds__(1024, 8) void attn14_kernel(const u16* __restrict__ Qh,
      const u16* __restrict__ Kh, const u16* __restrict__ Vt, u16* __restrict__ ctxb){
  __shared__ __align__(16) u32 smem[20480];    // 81,920 B
  u16*  Pm    = (u16*)smem;                    // [16][2048] fp16 probs (overlays key stripe)
  float* psum = (float*)(smem + 16384);        // [4][16][64] f32 (phase D/E, overlays cand)

  const int q0 = blockIdx.x * 16;
  const int h = blockIdx.y, b = blockIdx.z, bh = b * NH + h;
  const int t = threadIdx.x, lane = t & 63, w = t >> 6;
  const u16* Qb  = Qh + ((size_t)bh * SEQ + q0) * HD;
  const u16* Kb  = Kh + (size_t)bh * SEQ * HD;
  const u16* Vtb = Vt + (size_t)bh * HD * SEQ;

  // ---- phase A: QK^T -> monotone u16 keys. wave w covers keys [w*128, w*128+128), 16 queries.
  {
    const int qcol = lane & 15;
    const bf16x8 qa0 = *(const bf16x8*)(Qb + qcol * HD + (lane >> 4) * 8);
    const bf16x8 qa1 = *(const bf16x8*)(Qb + qcol * HD + 32 + (lane >> 4) * 8);
    #pragma unroll 4
    for (int tile = 0; tile < 8; ++tile){
      const int kr = w * 128 + tile * 16 + (lane & 15);
      const bf16x8 ka0 = *(const bf16x8*)(Kb + (size_t)kr * HD + (lane >> 4) * 8);
      const bf16x8 ka1 = *(const bf16x8*)(Kb + (size_t)kr * HD + 32 + (lane >> 4) * 8);
      f32x4 d = {};
      d = __builtin_amdgcn_mfma_f32_16x16x32_bf16(ka0, qa0, d, 0, 0, 0);
      d = __builtin_amdgcn_mfma_f32_16x16x32_bf16(ka1, qa1, d, 0, 0, 0);
      const int kbase = w * 128 + tile * 16 + (lane >> 4) * 4;
      const auto p01 = __builtin_amdgcn_cvt_pkrtz(d[0] * SCALEF, d[1] * SCALEF);
      const auto p23 = __builtin_amdgcn_cvt_pkrtz(d[2] * SCALEF, d[3] * SCALEF);
      u32 lo = __builtin_bit_cast(u32, p01);
      u32 hi = __builtin_bit_cast(u32, p23);
      const u32 s0 = (lo >> 15) & 0x00010001u;
      const u32 s1 = (hi >> 15) & 0x00010001u;
      lo ^= 0x80008000u | (s0 * 0x7fffu);     // per-half monotone map
      hi ^= 0x80008000u | (s1 * 0x7fffu);
      const int off = (qcol << 10) | ((kbase >> 1) ^ (qcol << 2));   // uint4-granular swizzle
      *(u64*)(smem + off) = (u64)lo | ((u64)hi << 32);
    }
  }
  __syncthreads();

  // ---- wave w owns query w. Row accessors (key domain).
  const int qi = q0 + w;
  uint4* row4 = (uint4*)smem + (w << 8);   // 256 uint4 per row
  u32*  rowp  = smem + (w << 10);
  u32*  cand  = smem + 16384 + (w << 8);   // wave-private 256 dwords
  const int x4 = w;                         // uint4-index xor (== dword xor w<<2)

  // ---- merged bracket+compact: find blo with count(>=blo) in [64,240];
  // successful probe writes candidates in the same pass (failed probes don't write).
  // Seed = fixed key 0xBE00 (score 1.5; scores ~N(0,1) => count ~137).
  u32 blo = 0;
  u32 bhi = 0x10000u; int c_hi = 0;
  int n_c = 0;
  {
    u32 tm = 0xBE00u;
    #pragma unroll 1
    for (int it = 0; it < 14; ++it){
      __asm__ volatile("" ::: "memory");     // force LDS re-read (no reg caching -> no spill)
      int cl = 0;
      #pragma unroll
      for (int ii = 0; ii < 4; ++ii){
        const uint4 v = row4[(lane + 64 * ii) ^ x4];
        cl += cnt_ge(v.x, tm) + cnt_ge(v.y, tm) + cnt_ge(v.z, tm) + cnt_ge(v.w, tm);
      }
      const int incl = dpp_scan_incl(cl);    // prefix AND total in ONE chain
      const int c = __builtin_amdgcn_readlane(incl, 63);
      if (c >= 64){
        int pos = incl - cl;
        __asm__ volatile("" ::: "memory");
        #pragma unroll
        for (int ii = 0; ii < 4; ++ii){
          const uint4 v = row4[(lane + 64 * ii) ^ x4];
          const u32 dws[4] = {v.x, v.y, v.z, v.w};
          #pragma unroll
          for (int c4 = 0; c4 < 4; ++c4){
            #pragma unroll
            for (int hh = 0; hh < 2; ++hh){
              const u32 kk = hh ? (dws[c4] >> 16) : (dws[c4] & 0xffffu);
              if (kk >= tm && pos < 256){
                const int idx = 8 * (lane + 64 * ii) + 2 * c4 + hh;
                cand[pos] = (kk << 16) | (u32)(2047 - idx);
                ++pos;
              }
            }
          }
        }
        blo = tm;
        n_c = c < 256 ? c : 256;
        if (c <= 240) break;
      } else {
        bhi = tm; c_hi = c;
      }
      const u32 nt = (blo + bhi) >> 1;
      if (nt == blo) break;
      tm = nt;
    }
    // safety fallback (never taken for real data): compact everything at key>=0
    if (n_c == 0){
      int cl = 32;
      const int incl = dpp_scan_incl(cl);
      int pos = incl - cl;
      __asm__ volatile("" ::: "memory");
      #pragma unroll
      for (int ii = 0; ii < 4; ++ii){
        const uint4 v = row4[(lane + 64 * ii) ^ x4];
        const u32 dws[4] = {v.x, v.y, v.z, v.w};
        #pragma unroll
        for (int c4 = 0; c4 < 4; ++c4){
          #pragma unroll
          for (int hh = 0; hh < 2; ++hh){
            const u32 kk = hh ? (dws[c4] >> 16) : (dws[c4] & 0xffffu);
            if (pos < 256){
              const int idx = 8 * (lane + 64 * ii) + 2 * c4 + hh;
              cand[pos] = (kk << 16) | (u32)(2047 - idx);
              ++pos;
            }
          }
        }
      }
      n_c = 256; blo = 0;
    }
  }
  __asm__ volatile("s_waitcnt lgkmcnt(0)" ::: "memory");

  // ---- load 4 candidates/lane; row max (== max candidate) -> m1 AND bisect upper bound
  u32 cj[4];
  #pragma unroll
  for (int j = 0; j < 4; ++j){
    const int s = lane + 64 * j;
    const u32 vv = cand[s];
    cj[j] = (s < n_c) ? vv : 0u;
  }
  u32 mk0 = cj[0] >> 16;
  #pragma unroll
  for (int j = 1; j < 4; ++j){ const u32 k2 = cj[j] >> 16; mk0 = k2 > mk0 ? k2 : mk0; }
  const u32 mkk = (u32)dpp_maxi((int)mk0);
  const float m1 = kval(mkk);
  if (mkk + 1u < bhi) bhi = mkk + 1u;    // tighten span: bisect ~9 iters

  // ---- exact bisect for T on candidates: ballot+popcount
  while (bhi - blo > 1u){
    const u32 tm = (blo + bhi) >> 1;
    const u32 kthr = tm << 16;
    const u64 b0 = __ballot(cj[0] >= kthr);
    const u64 b1 = __ballot(cj[1] >= kthr);
    const u64 b2 = __ballot(cj[2] >= kthr);
    const u64 b3 = __ballot(cj[3] >= kthr);
    const int c = __popcll(b0) + __popcll(b1) + __popcll(b2) + __popcll(b3);
    if (c >= 64){ blo = tm; } else { bhi = tm; c_hi = c; }
  }
  const u32 T = blo;          // exact 64th-largest fp16 key
  const int G = c_hi;         // count(> T)
  const int r_need = 64 - G;  // ties to take

  // ---- sparse softmax pieces from registers (tie-prefix via ballot)
  float ev[4];
  float zl = 0.f;
  const u64 lt_mask = (1ull << lane) - 1ull;
  int pre_eq = 0;
  #pragma unroll
  for (int j = 0; j < 4; ++j){
    const u32 key = cj[j] >> 16;
    ev[j] = __expf(kval(key) - m1);
    zl += (key > T) ? ev[j] : 0.f;
    const u64 be = __ballot(key == T);
    pre_eq += (int)__popcll(be & lt_mask);
  }
  const float eT = __expf(kval(T) - m1);
  const float Z1 = dpp_sumf(zl) + (float)r_need * eT;
  const float inv1 = 0.5f / Z1;

  // ---- windowed causal branch: softmax shifted by m1 (row max >= window max; shift-invariant)
  const int start = (qi - 256 > 0) ? (qi - 256) : 0;
  float wvv[5];
  float zs = 0.f;
  #pragma unroll
  for (int it = 0; it < 5; ++it){
    const int c0 = start + lane + it * 64;
    const int c = (c0 <= qi) ? c0 : qi;
    const u32 dw = rowp[(c >> 1) ^ (w << 2)];
    const u32 kk = (c & 1) ? (dw >> 16) : (dw & 0xffffu);
    const float e = __expf(kval(kk) - m1);
    wvv[it] = e;
    zs += (c0 <= qi) ? e : 0.f;
  }
  zs = dpp_sumf(zs);
  const float inv = 0.5f / zs;

  // ---- build P row w in place: zero, window scatter, sparse scatter-add
  {
    uint4* prow = (uint4*)(Pm + (w << 11));
    const uint4 z4 = {0u, 0u, 0u, 0u};
    #pragma unroll
    for (int i = 0; i < 4; ++i) prow[lane + i * 64] = z4;
    __asm__ volatile("" ::: "memory");
    #pragma unroll
    for (int it = 0; it < 5; ++it){
      const int c = start + lane + it * 64;
      if (c <= qi) Pm[pb_off(w, c)] = f2h(wvv[it] * inv);
    }
    __asm__ volatile("" ::: "memory");
    int rloc = pre_eq;
    #pragma unroll
    for (int j = 0; j < 4; ++j){
      const u32 key = cj[j] >> 16;
      const bool isgt = key > T;
      const bool iseq = (key == T);
      const bool sel = isgt || (iseq && rloc < r_need);
      if (iseq) ++rloc;
      if (sel){
        const int idx = 2047 - (int)(cj[j] & 0x7ffu);
        u16* cell = &Pm[pb_off(w, idx)];
        *cell = f2h(h2f(*cell) + ev[j] * inv1);
      }
    }
  }
  __syncthreads();

  // ---- phase D: PV via fp16 MFMA. out^T[d][q] = V^T · P^T. 4-way K-split.
  {
    const int kc = w >> 2, mi = w & 3;
    f32x4 acc = {};
    __builtin_amdgcn_s_setprio(1);
    #pragma unroll 4
    for (int ks = 0; ks < 16; ++ks){
      const int kk = kc * 512 + ks * 32;
      const h16x8 va = *(const h16x8*)(Vtb + (size_t)(mi * 16 + (lane & 15)) * SEQ + kk + (lane >> 4) * 8);
      const h16x8 pf = *(const h16x8*)&Pm[pb_off(lane & 15, kk + (lane >> 4) * 8)];
      acc = __builtin_amdgcn_mfma_f32_16x16x32_f16(va, pf, acc, 0, 0, 0);
    }
    __builtin_amdgcn_s_setprio(0);
    const int q = lane & 15, dbase = mi * 16 + (lane >> 4) * 4;
    *(f32x4*)&psum[ps_off(kc, q, dbase)] = acc;
  }
  __syncthreads();

  // ---- phase E: reduce 4 K-copies, write bf16 ctx
  {
    const int q = t >> 6, d = t & 63;
    const float r = psum[ps_off(0, q, d)] + psum[ps_off(1, q, d)]
                  + psum[ps_off(2, q, d)] + psum[ps_off(3, q, d)];
    ctxb[((size_t)(b * SEQ + q0 + q)) * DM + h * HD + d] = f2bf(r);
  }
}

// ---------------------------------------------------------------- host
extern "C" void kernel_launch(void* const* d_in, const int* in_sizes, int n_in,
                              void* d_out, int out_size, void* d_ws, size_t ws_size,
                              hipStream_t stream){
  const float* q_in = (const float*)d_in[0];
  const float* k_in = (const float*)d_in[1];
  const float* v_in = (const float*)d_in[2];
  const float* Wq = (const float*)d_in[3];
  const float* bq = (const float*)d_in[4];
  const float* Wk = (const float*)d_in[5];
  const float* bk = (const float*)d_in[6];
  const float* Wv = (const float*)d_in[7];
  const float* bv = (const float*)d_in[8];
  const float* Wo = (const float*)d_in[9];
  const float* bo = (const float*)d_in[10];

  char* ws = (char*)d_ws;
  u16* Xb   = (u16*)ws;                                   // 3 x 4096x768 bf16
  u16* Wb   = (u16*)(ws + 18874368);                      // 4 x 768x768 bf16
  u16* QKVh = (u16*)(ws + 23592960);                      // Q,K head-split bf16; slot2 = V^T fp16
  u16* ctxb = (u16*)(ws + 42467328);                      // 4096x768 bf16

  cvt_kernel<<<dim3(3145728 / 1024, 3), 256, 0, stream>>>(
      q_in, k_in, v_in, nullptr, Xb, Xb + 3145728, Xb + 2 * 3145728, nullptr, 3145728);
  cvt_kernel<<<dim3(589824 / 1024, 4), 256, 0, stream>>>(
      Wq, Wk, Wv, Wo, Wb, Wb + 589824, Wb + 2 * 589824, Wb + 3 * 589824, 589824);

  gemm_bt<0><<<dim3(32, 6, 3), 256, 0, stream>>>(Xb, Wb, bq, bk, bv, QKVh, nullptr);

  attn14_kernel<<<dim3(SEQ / 16, NH, BATCH), 1024, 0, stream>>>(
      QKVh, QKVh + 3145728, QKVh + 2 * 3145728, ctxb);

  gemm_bt<1><<<dim3(32, 6, 1), 256, 0, stream>>>(
      ctxb, Wb + 3 * 589824, bo, bo, bo, nullptr, (float*)d_out);
}

// Round 17
// 274.273 us; speedup vs baseline: 1.1002x; 1.1002x over previous
//
#include <hip/hip_runtime.h>
#include <hip/hip_fp16.h>
#include <stdint.h>
#include <math.h>

#define NH    12
#define SEQ   2048
#define BATCH 2
#define DM    768
#define HD    64
#define SCALEF 0.125f      // 1/sqrt(64)

typedef unsigned short u16;
typedef unsigned int   u32;
typedef unsigned long long u64;
typedef __attribute__((ext_vector_type(8))) short bf16x8;
typedef __attribute__((ext_vector_type(8))) _Float16 h16x8;
typedef __attribute__((ext_vector_type(2))) unsigned short u16x2;
typedef __attribute__((ext_vector_type(4))) float f32x4;

__device__ __forceinline__ u16 f2bf(float f){
  u32 u = __float_as_uint(f);
  u32 r = u + 0x7fffu + ((u >> 16) & 1u);
  return (u16)(r >> 16);
}
__device__ __forceinline__ u16 f2h(float f){ return __half_as_ushort(__float2half(f)); }
__device__ __forceinline__ float h2f(u16 x){ return __half2float(__ushort_as_half(x)); }

// async global->LDS 16B (HW: wave-uniform LDS base + lane*16; global src per-lane)
__device__ __forceinline__ void gload16(const u16* g, u16* l){
  __builtin_amdgcn_global_load_lds(
      (const __attribute__((address_space(1))) unsigned int*)g,
      (__attribute__((address_space(3))) unsigned int*)l, 16, 0, 0);
}

// order-preserving u16 key -> fp16 value
__device__ __forceinline__ float kval(u32 k){
  const u16 hb = (k & 0x8000u) ? (u16)(k & 0x7fffu) : (u16)(~k & 0xffffu);
  return h2f(hb);
}
__device__ __forceinline__ int cnt_ge(u32 dw, u32 tm){
  return (int)((dw & 0xffffu) >= tm) + (int)((dw >> 16) >= tm);
}

// ---- DPP wave64 reductions (VALU pipe, no LDS) ----
__device__ __forceinline__ int dpp_sumi(int x){
  x += __builtin_amdgcn_update_dpp(0, x, 0x111, 0xf, 0xf, true);   // row_shr:1
  x += __builtin_amdgcn_update_dpp(0, x, 0x112, 0xf, 0xf, true);   // row_shr:2
  x += __builtin_amdgcn_update_dpp(0, x, 0x114, 0xf, 0xf, true);   // row_shr:4
  x += __builtin_amdgcn_update_dpp(0, x, 0x118, 0xf, 0xf, true);   // row_shr:8
  x += __builtin_amdgcn_update_dpp(0, x, 0x142, 0xa, 0xf, true);   // row_bcast:15
  x += __builtin_amdgcn_update_dpp(0, x, 0x143, 0xc, 0xf, true);   // row_bcast:31
  return __builtin_amdgcn_readlane(x, 63);
}
__device__ __forceinline__ int dpp_scan_incl(int x){
  x += __builtin_amdgcn_update_dpp(0, x, 0x111, 0xf, 0xf, true);
  x += __builtin_amdgcn_update_dpp(0, x, 0x112, 0xf, 0xf, true);
  x += __builtin_amdgcn_update_dpp(0, x, 0x114, 0xf, 0xf, true);
  x += __builtin_amdgcn_update_dpp(0, x, 0x118, 0xf, 0xf, true);
  x += __builtin_amdgcn_update_dpp(0, x, 0x142, 0xa, 0xf, true);
  x += __builtin_amdgcn_update_dpp(0, x, 0x143, 0xc, 0xf, true);
  return x;
}
__device__ __forceinline__ float dpp_sumf(float x){
  #define ASTEP(ctrl, rm) x += __int_as_float(__builtin_amdgcn_update_dpp(0, __float_as_int(x), ctrl, rm, 0xf, true));
  ASTEP(0x111,0xf) ASTEP(0x112,0xf) ASTEP(0x114,0xf) ASTEP(0x118,0xf) ASTEP(0x142,0xa) ASTEP(0x143,0xc)
  #undef ASTEP
  return __uint_as_float((u32)__builtin_amdgcn_readlane(__float_as_int(x), 63));
}
__device__ __forceinline__ float dpp_maxf(float x){
  #define MSTEP(ctrl, rm) { int o = __float_as_int(x); \
    x = fmaxf(x, __int_as_float(__builtin_amdgcn_update_dpp(o, o, ctrl, rm, 0xf, false))); }
  MSTEP(0x111,0xf) MSTEP(0x112,0xf) MSTEP(0x114,0xf) MSTEP(0x118,0xf) MSTEP(0x142,0xa) MSTEP(0x143,0xc)
  #undef MSTEP
  return __uint_as_float((u32)__builtin_amdgcn_readlane(__float_as_int(x), 63));
}
__device__ __forceinline__ int dpp_maxi(int x){
  #define ISTEP(ctrl, rm) { int o = x; int y = __builtin_amdgcn_update_dpp(o, o, ctrl, rm, 0xf, false); \
    x = (x > y) ? x : y; }
  ISTEP(0x111,0xf) ISTEP(0x112,0xf) ISTEP(0x114,0xf) ISTEP(0x118,0xf) ISTEP(0x142,0xa) ISTEP(0x143,0xc)
  #undef ISTEP
  return __builtin_amdgcn_readlane(x, 63);
}

// swizzled fp16 prob matrix P[16][2048] (u16 units)
__device__ __forceinline__ int pb_off(int q, int k){
  return (q << 11) + ((((k >> 3) ^ (q & 7)) << 3) | (k & 7));
}
// swizzled psum [4 kcopies][16 q][64 d] (f32 units)
__device__ __forceinline__ int ps_off(int kc, int q, int d){
  return (kc << 10) + (q << 6) + ((((d >> 2) ^ q) & 15) << 2) + (d & 3);
}

// ---------------------------------------------------------------- cvt fp32->bf16
__global__ void cvt_kernel(const float* s0, const float* s1, const float* s2, const float* s3,
                           u16* d0, u16* d1, u16* d2, u16* d3, int n){
  const float* s; u16* d;
  switch (blockIdx.y){
    case 0: s = s0; d = d0; break;
    case 1: s = s1; d = d1; break;
    case 2: s = s2; d = d2; break;
    default: s = s3; d = d3; break;
  }
  int i = (blockIdx.x * 256 + threadIdx.x) * 4;
  if (i < n){
    float4 v = *(const float4*)(s + i);
    ushort4 o;
    o.x = f2bf(v.x); o.y = f2bf(v.y); o.z = f2bf(v.z); o.w = f2bf(v.w);
    *(ushort4*)(d + i) = o;
  }
}

// ---------------------------------------------------------------- GEMM  C = A @ W^T (+bias)
// Staging via global_load_lds width=16 (linear LDS [128][32], no padding).
// MODE 0: zz=0,1 -> bf16 head-split [(b*NH+h)*SEQ+s]*HD+d ; zz=2 -> fp16 V^T [(b*NH+h)*HD+d]*SEQ+s
// MODE 1: out fp32 plain [m][n]
template<int MODE>
__global__ __launch_bounds__(256) void gemm_bt(const u16* __restrict__ Aall, const u16* __restrict__ Wall,
      const float* __restrict__ bz0, const float* __restrict__ bz1, const float* __restrict__ bz2,
      u16* __restrict__ outb, float* __restrict__ outf){
  __shared__ u16 As[128 * 32];
  __shared__ u16 Bs[128 * 32];
  const int zz = blockIdx.z;
  const u16* A = Aall + (size_t)zz * 4096 * 768;
  const u16* W = Wall + (size_t)zz * 768 * 768;
  const float* bias = (zz == 0) ? bz0 : (zz == 1 ? bz1 : bz2);
  const int m0 = blockIdx.x * 128, n0 = blockIdx.y * 128;
  const int t = threadIdx.x, lane = t & 63, wv = t >> 6;
  const int wm = wv >> 1, wn = wv & 1;
  f32x4 acc[4][4] = {};
  const int srow = t >> 2;              // staged row 0..63 (call j adds 64)
  const int scol = (t & 3) * 8;         // bf16 col within 32
  const u16* ag = A + (size_t)(m0 + srow) * 768 + scol;
  const u16* bg = W + (size_t)(n0 + srow) * 768 + scol;
  u16* al = As + t * 8;                 // linear: u16 off t*8 == srow*32 + scol
  u16* bl = Bs + t * 8;
  for (int kt = 0; kt < 768; kt += 32){
    __syncthreads();                    // prior reads done before overwrite
    gload16(ag + kt,            al);
    gload16(ag + kt + 64 * 768, al + 2048);
    gload16(bg + kt,            bl);
    gload16(bg + kt + 64 * 768, bl + 2048);
    __syncthreads();                    // drains vmcnt -> LDS ready
    bf16x8 af[4], bq[4];
    #pragma unroll
    for (int i = 0; i < 4; ++i) af[i] = *(const bf16x8*)&As[(wm*64 + i*16 + (lane & 15)) * 32 + (lane >> 4) * 8];
    #pragma unroll
    for (int i = 0; i < 4; ++i) bq[i] = *(const bf16x8*)&Bs[(wn*64 + i*16 + (lane & 15)) * 32 + (lane >> 4) * 8];
    #pragma unroll
    for (int mi = 0; mi < 4; ++mi)
      #pragma unroll
      for (int ni = 0; ni < 4; ++ni)
        acc[mi][ni] = __builtin_amdgcn_mfma_f32_16x16x32_bf16(af[mi], bq[ni], acc[mi][ni], 0, 0, 0);
  }
  #pragma unroll
  for (int mi = 0; mi < 4; ++mi){
    #pragma unroll
    for (int ni = 0; ni < 4; ++ni){
      const int n = n0 + wn*64 + ni*16 + (lane & 15);
      const float bval = bias[n];
      const int mbase = m0 + wm*64 + mi*16 + (lane >> 4) * 4;
      if (MODE == 0 && zz == 2){
        const int bb = mbase >> 11, ss = mbase & 2047;
        const int hh = n >> 6, dd = n & 63;
        u64 pk = 0;
        #pragma unroll
        for (int r = 0; r < 4; ++r) pk |= (u64)f2h(acc[mi][ni][r] + bval) << (16 * r);
        *(u64*)(outb + (size_t)2 * 3145728 + (((size_t)(bb * NH + hh) * HD + dd) * SEQ + ss)) = pk;
      } else if (MODE == 0){
        #pragma unroll
        for (int r = 0; r < 4; ++r){
          const int m = mbase + r;
          const int bb = m >> 11, ss = m & 2047, hh = n >> 6, dd = n & 63;
          outb[(size_t)zz * 3145728 + (((size_t)bb * NH + hh) * SEQ + ss) * HD + dd] = f2bf(acc[mi][ni][r] + bval);
        }
      } else {
        #pragma unroll
        for (int r = 0; r < 4; ++r){
          const int m = mbase + r;
          outf[(size_t)m * DM + n] = acc[mi][ni][r] + bval;
        }
      }
    }
  }
}

// ---------------------------------------------------------------- fused attention v13 (final)
// Separate bracket probe + compact pass; bisect clamped to max-candidate key;
// ballot-based counting in bisect + tie-prefix.
__global__ __launch_bounds__(1024, 8) void attn13_kernel(const u16* __restrict__ Qh,
      const u16* __restrict__ Kh, const u16* __restrict__ Vt, u16* __restrict__ ctxb){
  __shared__ __align__(16) u32 smem[20480];    // 81,920 B
  u16*  Pm    = (u16*)smem;                    // [16][2048] fp16 probs (overlays key stripe)
  float* psum = (float*)(smem + 16384);        // [4][16][64] f32 (phase D/E, overlays cand)

  const int q0 = blockIdx.x * 16;
  const int h = blockIdx.y, b = blockIdx.z, bh = b * NH + h;
  const int t = threadIdx.x, lane = t & 63, w = t >> 6;
  const u16* Qb  = Qh + ((size_t)bh * SEQ + q0) * HD;
  const u16* Kb  = Kh + (size_t)bh * SEQ * HD;
  const u16* Vtb = Vt + (size_t)bh * HD * SEQ;

  // ---- phase A: QK^T -> monotone u16 keys. wave w covers keys [w*128, w*128+128), 16 queries.
  {
    const int qcol = lane & 15;
    const bf16x8 qa0 = *(const bf16x8*)(Qb + qcol * HD + (lane >> 4) * 8);
    const bf16x8 qa1 = *(const bf16x8*)(Qb + qcol * HD + 32 + (lane >> 4) * 8);
    #pragma unroll 4
    for (int tile = 0; tile < 8; ++tile){
      const int kr = w * 128 + tile * 16 + (lane & 15);
      const bf16x8 ka0 = *(const bf16x8*)(Kb + (size_t)kr * HD + (lane >> 4) * 8);
      const bf16x8 ka1 = *(const bf16x8*)(Kb + (size_t)kr * HD + 32 + (lane >> 4) * 8);
      f32x4 d = {};
      d = __builtin_amdgcn_mfma_f32_16x16x32_bf16(ka0, qa0, d, 0, 0, 0);
      d = __builtin_amdgcn_mfma_f32_16x16x32_bf16(ka1, qa1, d, 0, 0, 0);
      const int kbase = w * 128 + tile * 16 + (lane >> 4) * 4;
      const auto p01 = __builtin_amdgcn_cvt_pkrtz(d[0] * SCALEF, d[1] * SCALEF);
      const auto p23 = __builtin_amdgcn_cvt_pkrtz(d[2] * SCALEF, d[3] * SCALEF);
      u32 lo = __builtin_bit_cast(u32, p01);
      u32 hi = __builtin_bit_cast(u32, p23);
      const u32 s0 = (lo >> 15) & 0x00010001u;
      const u32 s1 = (hi >> 15) & 0x00010001u;
      lo ^= 0x80008000u | (s0 * 0x7fffu);     // per-half monotone map
      hi ^= 0x80008000u | (s1 * 0x7fffu);
      const int off = (qcol << 10) | ((kbase >> 1) ^ (qcol << 2));   // uint4-granular swizzle
      *(u64*)(smem + off) = (u64)lo | ((u64)hi << 32);
    }
  }
  __syncthreads();

  // ---- wave w owns query w. Row accessors (key domain).
  const int qi = q0 + w;
  uint4* row4 = (uint4*)smem + (w << 8);   // 256 uint4 per row
  u32*  rowp  = smem + (w << 10);
  u32*  cand  = smem + 16384 + (w << 8);   // wave-private 256 dwords
  const int x4 = w;                         // uint4-index xor (== dword xor w<<2)

  // ---- bracket search: find blo with count(>=blo) in [64,240]; KEEP per-lane count at blo.
  // Seed = fixed key 0xBE00 (score 1.5; scores ~N(0,1) => count ~137). No max pass needed.
  u32 blo = 0;
  u32 bhi = 0x10000u; int c_hi = 0;
  int cl_keep = 32;                          // valid for blo==0 (all keys >= 0)
  {
    u32 tm = 0xBE00u;
    #pragma unroll 1
    for (int it = 0; it < 14; ++it){
      __asm__ volatile("" ::: "memory");     // force LDS re-read (no reg caching -> no spill)
      int cl = 0;
      #pragma unroll
      for (int ii = 0; ii < 4; ++ii){
        const uint4 v = row4[(lane + 64 * ii) ^ x4];
        cl += cnt_ge(v.x, tm) + cnt_ge(v.y, tm) + cnt_ge(v.z, tm) + cnt_ge(v.w, tm);
      }
      const int c = dpp_sumi(cl);
      if (c >= 64){ blo = tm; cl_keep = cl; if (c <= 240) break; }
      else        { bhi = tm; c_hi = c; }
      const u32 nt = (blo + bhi) >> 1;
      if (nt == blo) break;
      tm = nt;
    }
  }

  // ---- compact candidates (key >= blo) to LDS as (key<<16)|(2047-idx) — single pass
  int n_c;
  {
    const int incl = dpp_scan_incl(cl_keep);
    const int totalc = __builtin_amdgcn_readlane(incl, 63);
    int pos = incl - cl_keep;
    __asm__ volatile("" ::: "memory");
    #pragma unroll
    for (int ii = 0; ii < 4; ++ii){
      const uint4 v = row4[(lane + 64 * ii) ^ x4];
      const u32 dws[4] = {v.x, v.y, v.z, v.w};
      #pragma unroll
      for (int c4 = 0; c4 < 4; ++c4){
        #pragma unroll
        for (int hh = 0; hh < 2; ++hh){
          const u32 kk = hh ? (dws[c4] >> 16) : (dws[c4] & 0xffffu);
          if (kk >= blo && pos < 256){
            const int idx = 8 * (lane + 64 * ii) + 2 * c4 + hh;
            cand[pos] = (kk << 16) | (u32)(2047 - idx);
            ++pos;
          }
        }
      }
    }
    n_c = totalc < 256 ? totalc : 256;
  }
  __asm__ volatile("s_waitcnt lgkmcnt(0)" ::: "memory");

  // ---- load 4 candidates/lane; row max (== max candidate) -> m1 AND bisect upper bound
  u32 cj[4];
  #pragma unroll
  for (int j = 0; j < 4; ++j){
    const int s = lane + 64 * j;
    const u32 vv = cand[s];
    cj[j] = (s < n_c) ? vv : 0u;
  }
  u32 mk0 = cj[0] >> 16;
  #pragma unroll
  for (int j = 1; j < 4; ++j){ const u32 k2 = cj[j] >> 16; mk0 = k2 > mk0 ? k2 : mk0; }
  const u32 mkk = (u32)dpp_maxi((int)mk0);
  const float m1 = kval(mkk);
  if (mkk + 1u < bhi) bhi = mkk + 1u;    // tighten span: bisect ~9 iters instead of ~14

  // ---- exact bisect for T on candidates: ballot+popcount (no DPP chain per iter)
  while (bhi - blo > 1u){
    const u32 tm = (blo + bhi) >> 1;
    const u32 kthr = tm << 16;
    const u64 b0 = __ballot(cj[0] >= kthr);
    const u64 b1 = __ballot(cj[1] >= kthr);
    const u64 b2 = __ballot(cj[2] >= kthr);
    const u64 b3 = __ballot(cj[3] >= kthr);
    const int c = __popcll(b0) + __popcll(b1) + __popcll(b2) + __popcll(b3);
    if (c >= 64){ blo = tm; } else { bhi = tm; c_hi = c; }
  }
  const u32 T = blo;          // exact 64th-largest fp16 key
  const int G = c_hi;         // count(> T)
  const int r_need = 64 - G;  // ties to take

  // ---- sparse softmax pieces from registers (tie-prefix via ballot; bit-identical)
  float ev[4];
  float zl = 0.f;
  const u64 lt_mask = (1ull << lane) - 1ull;
  int pre_eq = 0;
  #pragma unroll
  for (int j = 0; j < 4; ++j){
    const u32 key = cj[j] >> 16;
    ev[j] = __expf(kval(key) - m1);
    zl += (key > T) ? ev[j] : 0.f;
    const u64 be = __ballot(key == T);
    pre_eq += (int)__popcll(be & lt_mask);
  }
  const float eT = __expf(kval(T) - m1);
  const float Z1 = dpp_sumf(zl) + (float)r_need * eT;
  const float inv1 = 0.5f / Z1;

  // ---- windowed causal branch: read window keys, un-transform, softmax
  const int start = (qi - 256 > 0) ? (qi - 256) : 0;
  float wvv[5];
  #pragma unroll
  for (int it = 0; it < 5; ++it){
    const int c0 = start + lane + it * 64;
    const int c = (c0 <= qi) ? c0 : qi;
    const u32 dw = rowp[(c >> 1) ^ (w << 2)];
    const u32 kk = (c & 1) ? (dw >> 16) : (dw & 0xffffu);
    wvv[it] = (c0 <= qi) ? kval(kk) : -INFINITY;
  }
  float wm = -INFINITY;
  #pragma unroll
  for (int it = 0; it < 5; ++it) wm = fmaxf(wm, wvv[it]);
  wm = dpp_maxf(wm);
  float zs = 0.f;
  #pragma unroll
  for (int it = 0; it < 5; ++it){
    const int c = start + lane + it * 64;
    if (c <= qi){ const float e = __expf(wvv[it] - wm); wvv[it] = e; zs += e; }
  }
  zs = dpp_sumf(zs);
  const float inv = 0.5f / zs;

  // ---- build P row w in place: zero, window scatter, sparse scatter-add
  {
    uint4* prow = (uint4*)(Pm + (w << 11));
    const uint4 z4 = {0u, 0u, 0u, 0u};
    #pragma unroll
    for (int i = 0; i < 4; ++i) prow[lane + i * 64] = z4;
    __asm__ volatile("" ::: "memory");
    #pragma unroll
    for (int it = 0; it < 5; ++it){
      const int c = start + lane + it * 64;
      if (c <= qi) Pm[pb_off(w, c)] = f2h(wvv[it] * inv);
    }
    __asm__ volatile("" ::: "memory");
    int rloc = pre_eq;
    #pragma unroll
    for (int j = 0; j < 4; ++j){
      const u32 key = cj[j] >> 16;
      const bool isgt = key > T;
      const bool iseq = (key == T);
      const bool sel = isgt || (iseq && rloc < r_need);
      if (iseq) ++rloc;
      if (sel){
        const int idx = 2047 - (int)(cj[j] & 0x7ffu);
        u16* cell = &Pm[pb_off(w, idx)];
        *cell = f2h(h2f(*cell) + ev[j] * inv1);
      }
    }
  }
  __syncthreads();

  // ---- phase D: PV via fp16 MFMA. out^T[d][q] = V^T · P^T. 4-way K-split.
  {
    const int kc = w >> 2, mi = w & 3;
    f32x4 acc = {};
    __builtin_amdgcn_s_setprio(1);
    #pragma unroll 4
    for (int ks = 0; ks < 16; ++ks){
      const int kk = kc * 512 + ks * 32;
      const h16x8 va = *(const h16x8*)(Vtb + (size_t)(mi * 16 + (lane & 15)) * SEQ + kk + (lane >> 4) * 8);
      const h16x8 pf = *(const h16x8*)&Pm[pb_off(lane & 15, kk + (lane >> 4) * 8)];
      acc = __builtin_amdgcn_mfma_f32_16x16x32_f16(va, pf, acc, 0, 0, 0);
    }
    __builtin_amdgcn_s_setprio(0);
    const int q = lane & 15, dbase = mi * 16 + (lane >> 4) * 4;
    *(f32x4*)&psum[ps_off(kc, q, dbase)] = acc;
  }
  __syncthreads();

  // ---- phase E: reduce 4 K-copies, write bf16 ctx
  {
    const int q = t >> 6, d = t & 63;
    const float r = psum[ps_off(0, q, d)] + psum[ps_off(1, q, d)]
                  + psum[ps_off(2, q, d)] + psum[ps_off(3, q, d)];
    ctxb[((size_t)(b * SEQ + q0 + q)) * DM + h * HD + d] = f2bf(r);
  }
}

// ---------------------------------------------------------------- host
extern "C" void kernel_launch(void* const* d_in, const int* in_sizes, int n_in,
                              void* d_out, int out_size, void* d_ws, size_t ws_size,
                              hipStream_t stream){
  const float* q_in = (const float*)d_in[0];
  const float* k_in = (const float*)d_in[1];
  const float* v_in = (const float*)d_in[2];
  const float* Wq = (const float*)d_in[3];
  const float* bq = (const float*)d_in[4];
  const float* Wk = (const float*)d_in[5];
  const float* bk = (const float*)d_in[6];
  const float* Wv = (const float*)d_in[7];
  const float* bv = (const float*)d_in[8];
  const float* Wo = (const float*)d_in[9];
  const float* bo = (const float*)d_in[10];

  char* ws = (char*)d_ws;
  u16* Xb   = (u16*)ws;                                   // 3 x 4096x768 bf16
  u16* Wb   = (u16*)(ws + 18874368);                      // 4 x 768x768 bf16
  u16* QKVh = (u16*)(ws + 23592960);                      // Q,K head-split bf16; slot2 = V^T fp16
  u16* ctxb = (u16*)(ws + 42467328);                      // 4096x768 bf16

  cvt_kernel<<<dim3(3145728 / 1024, 3), 256, 0, stream>>>(
      q_in, k_in, v_in, nullptr, Xb, Xb + 3145728, Xb + 2 * 3145728, nullptr, 3145728);
  cvt_kernel<<<dim3(589824 / 1024, 4), 256, 0, stream>>>(
      Wq, Wk, Wv, Wo, Wb, Wb + 589824, Wb + 2 * 589824, Wb + 3 * 589824, 589824);

  gemm_bt<0><<<dim3(32, 6, 3), 256, 0, stream>>>(Xb, Wb, bq, bk, bv, QKVh, nullptr);

  attn13_kernel<<<dim3(SEQ / 16, NH, BATCH), 1024, 0, stream>>>(
      QKVh, QKVh + 3145728, QKVh + 2 * 3145728, ctxb);

  gemm_bt<1><<<dim3(32, 6, 1), 256, 0, stream>>>(
      ctxb, Wb + 3 * 589824, bo, bo, bo, nullptr, (float*)d_out);
}